// Round 6
// baseline (347.451 us; speedup 1.0000x reference)
//
#include <hip/hip_runtime.h>
#include <hip/hip_bf16.h>
#include <math.h>

#define Sd 8
#define Bd 1024
#define Ed 768
#define Hd 12
#define Dd 64
#define SBd 8192

typedef short bf16x8 __attribute__((ext_vector_type(8)));
typedef unsigned short u16x8 __attribute__((ext_vector_type(8)));
typedef float f32x4 __attribute__((ext_vector_type(4)));

// log2(e)/8 : folded into q so attention scores are exp2-ready
#define QSC 0.18033688011112043f

// lgkmcnt-only barrier: does NOT drain vmcnt -> in-flight global stores/loads
// keep streaming across tiles (T4: never drain vmcnt in the main loop).
#define BARRIER()                                        \
  do {                                                   \
    asm volatile("s_waitcnt lgkmcnt(0)" ::: "memory");   \
    __builtin_amdgcn_s_barrier();                        \
    asm volatile("" ::: "memory");                       \
  } while (0)

// RNE f32->bf16 (same rounding as __float2bfloat16, trivially-copyable types)
static __device__ __forceinline__ unsigned short f2bf(float f) {
  unsigned int u = __builtin_bit_cast(unsigned int, f);
  u += 0x7fffu + ((u >> 16) & 1u);
  return (unsigned short)(u >> 16);
}

static __device__ __forceinline__ unsigned int pk2(float lo, float hi) {
  return (unsigned int)f2bf(lo) | ((unsigned int)f2bf(hi) << 16);
}

static __device__ __forceinline__ float bflo(unsigned int u) {
  return __builtin_bit_cast(float, u << 16);
}
static __device__ __forceinline__ float bfhi(unsigned int u) {
  return __builtin_bit_cast(float, u & 0xffff0000u);
}

// ---------------------------------------------------------------------------
// QKV projection, 128x128 tile. X:(8192,768) f32, W:(768,768) f32.
// z=0: q -> [s][h][b][d] bf16 scaled by QSC; z=1: k -> [s][h][b][d];
// z=2: v -> [s][h][d][b] bf16 (transposed scatter epilogue).
// grid (64, 6, 3), block 256 (4 waves; wave = 64x64 output, 4x4 frags).
// ---------------------------------------------------------------------------
__global__ __launch_bounds__(256, 2) void qkv_kernel(
    const float* __restrict__ Qin, const float* __restrict__ Kin,
    const float* __restrict__ Vin,
    const float* __restrict__ Wq, const float* __restrict__ bq,
    const float* __restrict__ Wk, const float* __restrict__ bk,
    const float* __restrict__ Wv, const float* __restrict__ bv,
    unsigned short* __restrict__ qo, unsigned short* __restrict__ ko,
    unsigned short* __restrict__ vo) {
  __shared__ unsigned short As[128 * 72];
  __shared__ unsigned short Bs[128 * 72];
  const float* X;
  const float* W;
  const float* bias;
  switch (blockIdx.z) {
    case 0: X = Qin; W = Wq; bias = bq; break;
    case 1: X = Kin; W = Wk; bias = bk; break;
    default: X = Vin; W = Wv; bias = bv; break;
  }
  const int i0 = blockIdx.x * 128;
  const int j0 = blockIdx.y * 128;
  const int t = threadIdx.x;
  const int w = t >> 6, l = t & 63, lr = l & 15, lg = l >> 4;
  const int wr = w >> 1, wc = w & 1;

  f32x4 acc[4][4] = {};

  for (int k0 = 0; k0 < Ed; k0 += 64) {
    uint2 pa[8], pb[8];
#pragma unroll
    for (int q = 0; q < 8; ++q) {
      int flat = t + 256 * q;           // float4 units
      int row = flat >> 4;              // 0..127
      int c4 = (flat & 15) * 4;         // float col 0..60
      float4 va = *(const float4*)(X + (size_t)(i0 + row) * Ed + k0 + c4);
      float4 vb = *(const float4*)(W + (size_t)(j0 + row) * Ed + k0 + c4);
      pa[q] = make_uint2(pk2(va.x, va.y), pk2(va.z, va.w));
      pb[q] = make_uint2(pk2(vb.x, vb.y), pk2(vb.z, vb.w));
    }
    __syncthreads();
#pragma unroll
    for (int q = 0; q < 8; ++q) {
      int flat = t + 256 * q;
      int row = flat >> 4;
      int c4 = (flat & 15) * 4;
      *(uint2*)&As[row * 72 + c4] = pa[q];
      *(uint2*)&Bs[row * 72 + c4] = pb[q];
    }
    __syncthreads();
#pragma unroll
    for (int ks = 0; ks < 2; ++ks) {
      bf16x8 af[4], bf[4];
#pragma unroll
      for (int fr = 0; fr < 4; ++fr)
        af[fr] = *(const bf16x8*)&As[(wr * 64 + fr * 16 + lr) * 72 + ks * 32 + lg * 8];
#pragma unroll
      for (int fc = 0; fc < 4; ++fc)
        bf[fc] = *(const bf16x8*)&Bs[(wc * 64 + fc * 16 + lr) * 72 + ks * 32 + lg * 8];
#pragma unroll
      for (int fr = 0; fr < 4; ++fr)
#pragma unroll
        for (int fc = 0; fc < 4; ++fc)
          acc[fr][fc] = __builtin_amdgcn_mfma_f32_16x16x32_bf16(af[fr], bf[fc], acc[fr][fc], 0, 0, 0);
    }
  }

  const int z = blockIdx.z;
  if (z < 2) {
    unsigned short* out = (z == 0) ? qo : ko;
    const float sc = (z == 0) ? QSC : 1.0f;
#pragma unroll
    for (int fr = 0; fr < 4; ++fr) {
#pragma unroll
      for (int fc = 0; fc < 4; ++fc) {
        int colg = j0 + wc * 64 + fc * 16 + lr;
        int h = colg >> 6, d = colg & 63;
        float bv_ = bias[colg];
#pragma unroll
        for (int r = 0; r < 4; ++r) {
          int i = i0 + wr * 64 + fr * 16 + lg * 4 + r;
          int s = i >> 10, b = i & 1023;
          float v = (acc[fr][fc][r] + bv_) * sc;
          out[((((size_t)s * Hd + h) * Bd + b) << 6) + d] = f2bf(v);
        }
      }
    }
  } else {
#pragma unroll
    for (int fr = 0; fr < 4; ++fr) {
#pragma unroll
      for (int fc = 0; fc < 4; ++fc) {
        int colg = j0 + wc * 64 + fc * 16 + lr;
        int h = colg >> 6, d = colg & 63;
        float bv_ = bias[colg];
#pragma unroll
        for (int r = 0; r < 4; ++r) {
          int i = i0 + wr * 64 + fr * 16 + lg * 4 + r;
          int s = i >> 10, b = i & 1023;
          float v = acc[fr][fc][r] + bv_;
          vo[(((size_t)s * Hd + h) * 64 + d) * Bd + b] = f2bf(v);
        }
      }
    }
  }
}

// ---------------------------------------------------------------------------
// Attention per (s,h), SINGLE QK^T. Scores pre-scaled for exp2, no max
// tracking. Pass 1: stage K,V; QK^T once; p=exp2 packed bf16 held in 128
// VGPRs (fully unrolled ct -> compile-time indices); PV fused with
// UNNORMALIZED p; lsum accumulated. Epilogue scales ctx by 1/lsum.
// Pass 2: pure streaming nontemporal f32 stores of p*invl (no LDS/barriers).
// grid (16, 96), block 256 (4 waves x 16 q-rows).
// ---------------------------------------------------------------------------
__global__ __launch_bounds__(256) void attn_kernel(
    const unsigned short* __restrict__ qb, const unsigned short* __restrict__ kb,
    const unsigned short* __restrict__ vt, float* __restrict__ attn_out,
    unsigned short* __restrict__ ctx_out) {
  __shared__ unsigned short Ks[64 * 72];
  __shared__ unsigned short Vs[64 * 72];
  __shared__ unsigned short Pb[4][16 * 72];
  const int sh = blockIdx.y;
  const int s = sh / Hd, h = sh % Hd;
  const int row0 = blockIdx.x * 64;
  const size_t base = (size_t)sh * Bd * 64;
  const int t = threadIdx.x;
  const int w = t >> 6, l = t & 63, lr = l & 15, lg = l >> 4;
  const int srow = t >> 2, skg = (t & 3) << 4;

  const int qrow = row0 + w * 16 + lr;
  const bf16x8 aq0 = *(const bf16x8*)(qb + base + (size_t)qrow * 64 + lg * 8);
  const bf16x8 aq1 = *(const bf16x8*)(qb + base + (size_t)qrow * 64 + 32 + lg * 8);

  float lsum[4] = {0.f, 0.f, 0.f, 0.f};
  uint2 pst[16][4];              // packed bf16 p: [ct][c2] = {r0r1, r2r3}
  f32x4 cacc[4] = {};
  const unsigned short* vbase = vt + (size_t)sh * 64 * Bd;

  u16x8 k0, k1, v0, v1;
  {
    const unsigned short* kp = kb + base + (size_t)srow * 64 + skg;
    k0 = *(const u16x8*)kp;
    k1 = *(const u16x8*)(kp + 8);
    const unsigned short* vp = vbase + (size_t)srow * Bd + skg;  // V^T row d
    v0 = *(const u16x8*)vp;
    v1 = *(const u16x8*)(vp + 8);
  }
#pragma unroll
  for (int ct = 0; ct < 16; ++ct) {
    BARRIER();
    *(u16x8*)&Ks[srow * 72 + skg] = k0;
    *(u16x8*)&Ks[srow * 72 + skg + 8] = k1;
    *(u16x8*)&Vs[srow * 72 + skg] = v0;
    *(u16x8*)&Vs[srow * 72 + skg + 8] = v1;
    BARRIER();
    if (ct < 15) {
      const unsigned short* kn = kb + base + (size_t)((ct + 1) * 64 + srow) * 64 + skg;
      k0 = *(const u16x8*)kn;
      k1 = *(const u16x8*)(kn + 8);
      const unsigned short* vn = vbase + (size_t)srow * Bd + (ct + 1) * 64 + skg;
      v0 = *(const u16x8*)vn;
      v1 = *(const u16x8*)(vn + 8);
    }
    f32x4 scv[4] = {};
#pragma unroll
    for (int ks = 0; ks < 2; ++ks) {
      bf16x8 a = ks ? aq1 : aq0;
#pragma unroll
      for (int c2 = 0; c2 < 4; ++c2) {
        bf16x8 bb = *(const bf16x8*)&Ks[(c2 * 16 + lr) * 72 + ks * 32 + lg * 8];
        scv[c2] = __builtin_amdgcn_mfma_f32_16x16x32_bf16(a, bb, scv[c2], 0, 0, 0);
      }
    }
#pragma unroll
    for (int c2 = 0; c2 < 4; ++c2) {
      float p0 = __builtin_amdgcn_exp2f(scv[c2][0]);
      float p1 = __builtin_amdgcn_exp2f(scv[c2][1]);
      float p2 = __builtin_amdgcn_exp2f(scv[c2][2]);
      float p3 = __builtin_amdgcn_exp2f(scv[c2][3]);
      lsum[0] += p0; lsum[1] += p1; lsum[2] += p2; lsum[3] += p3;
      uint2 pp = make_uint2(pk2(p0, p1), pk2(p2, p3));
      pst[ct][c2] = pp;
      Pb[w][(lg * 4 + 0) * 72 + c2 * 16 + lr] = (unsigned short)(pp.x & 0xffffu);
      Pb[w][(lg * 4 + 1) * 72 + c2 * 16 + lr] = (unsigned short)(pp.x >> 16);
      Pb[w][(lg * 4 + 2) * 72 + c2 * 16 + lr] = (unsigned short)(pp.y & 0xffffu);
      Pb[w][(lg * 4 + 3) * 72 + c2 * 16 + lr] = (unsigned short)(pp.y >> 16);
    }
    // PV with UNNORMALIZED p (scaled by invl in epilogue). Pb is per-wave,
    // ds-ordering within the wave guarantees visibility (lgkmcnt).
#pragma unroll
    for (int ks2 = 0; ks2 < 2; ++ks2) {
      bf16x8 pa = *(const bf16x8*)&Pb[w][lr * 72 + ks2 * 32 + lg * 8];
#pragma unroll
      for (int dt = 0; dt < 4; ++dt) {
        bf16x8 bv = *(const bf16x8*)&Vs[(dt * 16 + lr) * 72 + ks2 * 32 + lg * 8];
        cacc[dt] = __builtin_amdgcn_mfma_f32_16x16x32_bf16(pa, bv, cacc[dt], 0, 0, 0);
      }
    }
  }

  float invl[4];
#pragma unroll
  for (int r = 0; r < 4; ++r) {
    float s1 = lsum[r];
    s1 += __shfl_xor(s1, 1, 16);
    s1 += __shfl_xor(s1, 2, 16);
    s1 += __shfl_xor(s1, 4, 16);
    s1 += __shfl_xor(s1, 8, 16);
    invl[r] = 1.0f / s1;  // uniform across each 16-lane group
  }

  // ctx write (normalized)
#pragma unroll
  for (int dt = 0; dt < 4; ++dt) {
#pragma unroll
    for (int r = 0; r < 4; ++r) {
      int row = row0 + w * 16 + lg * 4 + r;
      size_t i = (size_t)s * Bd + row;
      int j = h * 64 + dt * 16 + lr;
      ctx_out[i * Ed + j] = f2bf(cacc[dt][r] * invl[r]);
    }
  }

  // ---- pass 2: pure streaming attn store ----
  float* arow = attn_out + ((size_t)sh * Bd + row0 + w * 16 + lg * 4) * Bd + lr;
#pragma unroll
  for (int ct = 0; ct < 16; ++ct) {
#pragma unroll
    for (int c2 = 0; c2 < 4; ++c2) {
      uint2 pp = pst[ct][c2];
      int cb = ct * 64 + c2 * 16;
      __builtin_nontemporal_store(bflo(pp.x) * invl[0], arow + (size_t)0 * Bd + cb);
      __builtin_nontemporal_store(bfhi(pp.x) * invl[1], arow + (size_t)1 * Bd + cb);
      __builtin_nontemporal_store(bflo(pp.y) * invl[2], arow + (size_t)2 * Bd + cb);
      __builtin_nontemporal_store(bfhi(pp.y) * invl[3], arow + (size_t)3 * Bd + cb);
    }
  }
}

// ---------------------------------------------------------------------------
// Output projection, 128x128 tile: x[i,j] = sum_k ctx[i,k]*Wo[j,k]+bo[j]+Q[i,j]
// ctx bf16 (8192,768), Wo f32. grid (64, 6), block 256.
// ---------------------------------------------------------------------------
__global__ __launch_bounds__(256, 2) void proj_kernel(
    const unsigned short* __restrict__ ctx, const float* __restrict__ Wo,
    const float* __restrict__ bo, const float* __restrict__ Qin,
    float* __restrict__ xout) {
  __shared__ unsigned short As[128 * 72];
  __shared__ unsigned short Bs[128 * 72];
  const int i0 = blockIdx.x * 128;
  const int j0 = blockIdx.y * 128;
  const int t = threadIdx.x;
  const int w = t >> 6, l = t & 63, lr = l & 15, lg = l >> 4;
  const int wr = w >> 1, wc = w & 1;

  f32x4 acc[4][4] = {};

  for (int k0 = 0; k0 < Ed; k0 += 64) {
    u16x8 pa[4];
    uint2 pb[8];
#pragma unroll
    for (int q = 0; q < 4; ++q) {
      int flat = t + 256 * q;
      int row = flat >> 3;
      int c8 = (flat & 7) * 8;
      pa[q] = *(const u16x8*)(ctx + (size_t)(i0 + row) * Ed + k0 + c8);
    }
#pragma unroll
    for (int q = 0; q < 8; ++q) {
      int flat = t + 256 * q;
      int row = flat >> 4;
      int c4 = (flat & 15) * 4;
      float4 vb = *(const float4*)(Wo + (size_t)(j0 + row) * Ed + k0 + c4);
      pb[q] = make_uint2(pk2(vb.x, vb.y), pk2(vb.z, vb.w));
    }
    __syncthreads();
#pragma unroll
    for (int q = 0; q < 4; ++q) {
      int flat = t + 256 * q;
      int row = flat >> 3;
      int c8 = (flat & 7) * 8;
      *(u16x8*)&As[row * 72 + c8] = pa[q];
    }
#pragma unroll
    for (int q = 0; q < 8; ++q) {
      int flat = t + 256 * q;
      int row = flat >> 4;
      int c4 = (flat & 15) * 4;
      *(uint2*)&Bs[row * 72 + c4] = pb[q];
    }
    __syncthreads();
#pragma unroll
    for (int ks = 0; ks < 2; ++ks) {
      bf16x8 af[4], bf[4];
#pragma unroll
      for (int fr = 0; fr < 4; ++fr)
        af[fr] = *(const bf16x8*)&As[(wr * 64 + fr * 16 + lr) * 72 + ks * 32 + lg * 8];
#pragma unroll
      for (int fc = 0; fc < 4; ++fc)
        bf[fc] = *(const bf16x8*)&Bs[(wc * 64 + fc * 16 + lr) * 72 + ks * 32 + lg * 8];
#pragma unroll
      for (int fr = 0; fr < 4; ++fr)
#pragma unroll
        for (int fc = 0; fc < 4; ++fc)
          acc[fr][fc] = __builtin_amdgcn_mfma_f32_16x16x32_bf16(af[fr], bf[fc], acc[fr][fc], 0, 0, 0);
    }
  }

#pragma unroll
  for (int fr = 0; fr < 4; ++fr) {
#pragma unroll
    for (int fc = 0; fc < 4; ++fc) {
      int j = j0 + wc * 64 + fc * 16 + lr;
      float bv_ = bo[j];
#pragma unroll
      for (int r = 0; r < 4; ++r) {
        int i = i0 + wr * 64 + fr * 16 + lg * 4 + r;
        float v = acc[fr][fc][r] + bv_ + Qin[(size_t)i * Ed + j];
        xout[(size_t)i * Ed + j] = v;
      }
    }
  }
}

// ---------------------------------------------------------------------------
// Row LayerNorm over E=768.  grid (8192), block 256.
// ---------------------------------------------------------------------------
__global__ __launch_bounds__(256) void ln_kernel(
    const float* __restrict__ x, const float* __restrict__ g,
    const float* __restrict__ bb, float* __restrict__ out) {
  const int i = blockIdx.x;
  const int t = threadIdx.x;
  const float* xr = x + (size_t)i * Ed;
  float v0 = xr[t], v1 = xr[t + 256], v2 = xr[t + 512];
  float s1 = v0 + v1 + v2;
  float s2 = v0 * v0 + v1 * v1 + v2 * v2;
#pragma unroll
  for (int mk = 1; mk < 64; mk <<= 1) {
    s1 += __shfl_xor(s1, mk, 64);
    s2 += __shfl_xor(s2, mk, 64);
  }
  __shared__ float red[8];
  const int w = t >> 6, l = t & 63;
  if (l == 0) { red[w] = s1; red[w + 4] = s2; }
  __syncthreads();
  s1 = red[0] + red[1] + red[2] + red[3];
  s2 = red[4] + red[5] + red[6] + red[7];
  float mu = s1 * (1.0f / 768.0f);
  float var = s2 * (1.0f / 768.0f) - mu * mu;
  float rs = rsqrtf(var + 1e-5f);
  float* orow = out + (size_t)i * Ed;
  orow[t] = (v0 - mu) * rs * g[t] + bb[t];
  orow[t + 256] = (v1 - mu) * rs * g[t + 256] + bb[t + 256];
  orow[t + 512] = (v2 - mu) * rs * g[t + 512] + bb[t + 512];
}

extern "C" void kernel_launch(void* const* d_in, const int* in_sizes, int n_in,
                              void* d_out, int out_size, void* d_ws, size_t ws_size,
                              hipStream_t stream) {
  (void)in_sizes; (void)n_in; (void)out_size; (void)ws_size;
  const float* Qin = (const float*)d_in[0];
  const float* Kin = (const float*)d_in[1];
  const float* Vin = (const float*)d_in[2];
  const float* Wq = (const float*)d_in[3];
  const float* bq = (const float*)d_in[4];
  const float* Wk = (const float*)d_in[5];
  const float* bk = (const float*)d_in[6];
  const float* Wv = (const float*)d_in[7];
  const float* bv = (const float*)d_in[8];
  const float* Wo = (const float*)d_in[9];
  const float* bo = (const float*)d_in[10];
  const float* ln_g = (const float*)d_in[11];
  const float* ln_b = (const float*)d_in[12];

  float* outp = (float*)d_out;
  float* normed = outp;
  float* attn_out = outp + (size_t)SBd * Ed;

  char* ws = (char*)d_ws;
  unsigned short* qws = (unsigned short*)ws;
  unsigned short* kws = qws + 6291456;
  unsigned short* vws = kws + 6291456;   // [sh][d][b] transposed
  unsigned short* ctxws = vws + 6291456;
  float* xws = (float*)(ws + (size_t)4 * 12582912);

  dim3 blk(256);
  hipLaunchKernelGGL(qkv_kernel, dim3(64, 6, 3), blk, 0, stream,
                     Qin, Kin, Vin, Wq, bq, Wk, bk, Wv, bv, qws, kws, vws);
  hipLaunchKernelGGL(attn_kernel, dim3(16, 96), blk, 0, stream,
                     qws, kws, vws, attn_out, ctxws);
  hipLaunchKernelGGL(proj_kernel, dim3(64, 6), blk, 0, stream,
                     ctxws, Wo, bo, Qin, xws);
  hipLaunchKernelGGL(ln_kernel, dim3(8192), blk, 0, stream,
                     xws, ln_g, ln_b, normed);
}

// Round 7
// 262.071 us; speedup vs baseline: 1.3258x; 1.3258x over previous
//
#include <hip/hip_runtime.h>
#include <hip/hip_bf16.h>
#include <math.h>

#define Sd 8
#define Bd 1024
#define Ed 768
#define Hd 12
#define Dd 64
#define SBd 8192

typedef short bf16x8 __attribute__((ext_vector_type(8)));
typedef unsigned short u16x8 __attribute__((ext_vector_type(8)));
typedef float f32x4 __attribute__((ext_vector_type(4)));

// log2(e)/8 : folded into q so attention scores are exp2-ready
#define QSC 0.18033688011112043f

// lgkmcnt-only barrier: does NOT drain vmcnt -> in-flight global stores/loads
// keep streaming across tiles (T4: never drain vmcnt in the main loop).
#define BARRIER()                                        \
  do {                                                   \
    asm volatile("s_waitcnt lgkmcnt(0)" ::: "memory");   \
    __builtin_amdgcn_s_barrier();                        \
    asm volatile("" ::: "memory");                       \
  } while (0)

// RNE f32->bf16 (same rounding as __float2bfloat16, trivially-copyable types)
static __device__ __forceinline__ unsigned short f2bf(float f) {
  unsigned int u = __builtin_bit_cast(unsigned int, f);
  u += 0x7fffu + ((u >> 16) & 1u);
  return (unsigned short)(u >> 16);
}

static __device__ __forceinline__ unsigned int pk2(float lo, float hi) {
  return (unsigned int)f2bf(lo) | ((unsigned int)f2bf(hi) << 16);
}

// ---------------------------------------------------------------------------
// QKV projection, 128x128 tile. X:(8192,768) f32, W:(768,768) f32.
// z=0: q -> [s][h][b][d] bf16 scaled by QSC; z=1: k -> [s][h][b][d];
// z=2: v -> [s][h][d][b] bf16 (transposed scatter epilogue).
// grid (64, 6, 3), block 256 (4 waves; wave = 64x64 output, 4x4 frags).
// ---------------------------------------------------------------------------
__global__ __launch_bounds__(256, 2) void qkv_kernel(
    const float* __restrict__ Qin, const float* __restrict__ Kin,
    const float* __restrict__ Vin,
    const float* __restrict__ Wq, const float* __restrict__ bq,
    const float* __restrict__ Wk, const float* __restrict__ bk,
    const float* __restrict__ Wv, const float* __restrict__ bv,
    unsigned short* __restrict__ qo, unsigned short* __restrict__ ko,
    unsigned short* __restrict__ vo) {
  __shared__ unsigned short As[128 * 72];
  __shared__ unsigned short Bs[128 * 72];
  const float* X;
  const float* W;
  const float* bias;
  switch (blockIdx.z) {
    case 0: X = Qin; W = Wq; bias = bq; break;
    case 1: X = Kin; W = Wk; bias = bk; break;
    default: X = Vin; W = Wv; bias = bv; break;
  }
  const int i0 = blockIdx.x * 128;
  const int j0 = blockIdx.y * 128;
  const int t = threadIdx.x;
  const int w = t >> 6, l = t & 63, lr = l & 15, lg = l >> 4;
  const int wr = w >> 1, wc = w & 1;

  f32x4 acc[4][4] = {};

  for (int k0 = 0; k0 < Ed; k0 += 64) {
    uint2 pa[8], pb[8];
#pragma unroll
    for (int q = 0; q < 8; ++q) {
      int flat = t + 256 * q;           // float4 units
      int row = flat >> 4;              // 0..127
      int c4 = (flat & 15) * 4;         // float col 0..60
      float4 va = *(const float4*)(X + (size_t)(i0 + row) * Ed + k0 + c4);
      float4 vb = *(const float4*)(W + (size_t)(j0 + row) * Ed + k0 + c4);
      pa[q] = make_uint2(pk2(va.x, va.y), pk2(va.z, va.w));
      pb[q] = make_uint2(pk2(vb.x, vb.y), pk2(vb.z, vb.w));
    }
    __syncthreads();
#pragma unroll
    for (int q = 0; q < 8; ++q) {
      int flat = t + 256 * q;
      int row = flat >> 4;
      int c4 = (flat & 15) * 4;
      *(uint2*)&As[row * 72 + c4] = pa[q];
      *(uint2*)&Bs[row * 72 + c4] = pb[q];
    }
    __syncthreads();
#pragma unroll
    for (int ks = 0; ks < 2; ++ks) {
      bf16x8 af[4], bf[4];
#pragma unroll
      for (int fr = 0; fr < 4; ++fr)
        af[fr] = *(const bf16x8*)&As[(wr * 64 + fr * 16 + lr) * 72 + ks * 32 + lg * 8];
#pragma unroll
      for (int fc = 0; fc < 4; ++fc)
        bf[fc] = *(const bf16x8*)&Bs[(wc * 64 + fc * 16 + lr) * 72 + ks * 32 + lg * 8];
#pragma unroll
      for (int fr = 0; fr < 4; ++fr)
#pragma unroll
        for (int fc = 0; fc < 4; ++fc)
          acc[fr][fc] = __builtin_amdgcn_mfma_f32_16x16x32_bf16(af[fr], bf[fc], acc[fr][fc], 0, 0, 0);
    }
  }

  const int z = blockIdx.z;
  if (z < 2) {
    unsigned short* out = (z == 0) ? qo : ko;
    const float sc = (z == 0) ? QSC : 1.0f;
#pragma unroll
    for (int fr = 0; fr < 4; ++fr) {
#pragma unroll
      for (int fc = 0; fc < 4; ++fc) {
        int colg = j0 + wc * 64 + fc * 16 + lr;
        int h = colg >> 6, d = colg & 63;
        float bv_ = bias[colg];
#pragma unroll
        for (int r = 0; r < 4; ++r) {
          int i = i0 + wr * 64 + fr * 16 + lg * 4 + r;
          int s = i >> 10, b = i & 1023;
          float v = (acc[fr][fc][r] + bv_) * sc;
          out[((((size_t)s * Hd + h) * Bd + b) << 6) + d] = f2bf(v);
        }
      }
    }
  } else {
#pragma unroll
    for (int fr = 0; fr < 4; ++fr) {
#pragma unroll
      for (int fc = 0; fc < 4; ++fc) {
        int colg = j0 + wc * 64 + fc * 16 + lr;
        int h = colg >> 6, d = colg & 63;
        float bv_ = bias[colg];
#pragma unroll
        for (int r = 0; r < 4; ++r) {
          int i = i0 + wr * 64 + fr * 16 + lg * 4 + r;
          int s = i >> 10, b = i & 1023;
          float v = acc[fr][fc][r] + bv_;
          vo[(((size_t)s * Hd + h) * 64 + d) * Bd + b] = f2bf(v);
        }
      }
    }
  }
}

// ---------------------------------------------------------------------------
// Attention per (s,h). Two-pass (recompute QK^T), scores pre-scaled for exp2,
// no max tracking. QBLK=128: 8 waves x 16 q-rows; K/V staged once per 128
// rows. lgkmcnt-only barriers; reg prefetch; nontemporal attn stores.
// grid (8, 96), block 512.
// ---------------------------------------------------------------------------
__global__ __launch_bounds__(512) void attn_kernel(
    const unsigned short* __restrict__ qb, const unsigned short* __restrict__ kb,
    const unsigned short* __restrict__ vt, float* __restrict__ attn_out,
    unsigned short* __restrict__ ctx_out) {
  __shared__ unsigned short Ks[64 * 72];
  __shared__ unsigned short Vs[64 * 72];
  __shared__ unsigned short Pb[8][16 * 72];
  const int sh = blockIdx.y;
  const int s = sh / Hd, h = sh % Hd;
  const int row0 = blockIdx.x * 128;
  const size_t base = (size_t)sh * Bd * 64;
  const int t = threadIdx.x;
  const int w = t >> 6, l = t & 63, lr = l & 15, lg = l >> 4;
  const int srow = t >> 3, skg = (t & 7) * 8;   // 512 thr x 16B = one 8KB tile

  const int qrow = row0 + w * 16 + lr;
  const bf16x8 aq0 = *(const bf16x8*)(qb + base + (size_t)qrow * 64 + lg * 8);
  const bf16x8 aq1 = *(const bf16x8*)(qb + base + (size_t)qrow * 64 + 32 + lg * 8);

  float lsum[4] = {0.f, 0.f, 0.f, 0.f};

  // ---- pass 1: denominators ----
  {
    const unsigned short* kp = kb + base + (size_t)srow * 64 + skg;
    u16x8 k0 = *(const u16x8*)kp;
    for (int ct = 0; ct < 16; ++ct) {
      BARRIER();
      *(u16x8*)&Ks[srow * 72 + skg] = k0;
      BARRIER();
      if (ct < 15) {
        const unsigned short* kn = kb + base + (size_t)((ct + 1) * 64 + srow) * 64 + skg;
        k0 = *(const u16x8*)kn;
      }
      f32x4 scv[4] = {};
#pragma unroll
      for (int ks = 0; ks < 2; ++ks) {
        bf16x8 a = ks ? aq1 : aq0;
#pragma unroll
        for (int c2 = 0; c2 < 4; ++c2) {
          bf16x8 bb = *(const bf16x8*)&Ks[(c2 * 16 + lr) * 72 + ks * 32 + lg * 8];
          scv[c2] = __builtin_amdgcn_mfma_f32_16x16x32_bf16(a, bb, scv[c2], 0, 0, 0);
        }
      }
#pragma unroll
      for (int c2 = 0; c2 < 4; ++c2)
#pragma unroll
        for (int r = 0; r < 4; ++r)
          lsum[r] += __builtin_amdgcn_exp2f(scv[c2][r]);
    }
  }
#pragma unroll
  for (int r = 0; r < 4; ++r) {
    float s1 = lsum[r];
    s1 += __shfl_xor(s1, 1, 16);
    s1 += __shfl_xor(s1, 2, 16);
    s1 += __shfl_xor(s1, 4, 16);
    s1 += __shfl_xor(s1, 8, 16);
    lsum[r] = 1.0f / s1;  // inverse denom for row lg*4+r (uniform across lr)
  }

  // ---- pass 2: recompute, write attn (nontemporal), PV ----
  f32x4 cacc[4] = {};
  const unsigned short* vbase = vt + (size_t)sh * 64 * Bd;
  u16x8 k0, v0;
  {
    const unsigned short* kp = kb + base + (size_t)srow * 64 + skg;
    k0 = *(const u16x8*)kp;
    const unsigned short* vp = vbase + (size_t)srow * Bd + skg;  // V^T row d
    v0 = *(const u16x8*)vp;
  }
  for (int ct = 0; ct < 16; ++ct) {
    BARRIER();
    *(u16x8*)&Ks[srow * 72 + skg] = k0;
    *(u16x8*)&Vs[srow * 72 + skg] = v0;
    BARRIER();
    if (ct < 15) {
      const unsigned short* kn = kb + base + (size_t)((ct + 1) * 64 + srow) * 64 + skg;
      k0 = *(const u16x8*)kn;
      const unsigned short* vn = vbase + (size_t)srow * Bd + (ct + 1) * 64 + skg;
      v0 = *(const u16x8*)vn;
    }
    f32x4 scv[4] = {};
#pragma unroll
    for (int ks = 0; ks < 2; ++ks) {
      bf16x8 a = ks ? aq1 : aq0;
#pragma unroll
      for (int c2 = 0; c2 < 4; ++c2) {
        bf16x8 bb = *(const bf16x8*)&Ks[(c2 * 16 + lr) * 72 + ks * 32 + lg * 8];
        scv[c2] = __builtin_amdgcn_mfma_f32_16x16x32_bf16(a, bb, scv[c2], 0, 0, 0);
      }
    }
#pragma unroll
    for (int c2 = 0; c2 < 4; ++c2) {
#pragma unroll
      for (int r = 0; r < 4; ++r) {
        float p = __builtin_amdgcn_exp2f(scv[c2][r]) * lsum[r];
        int row = row0 + w * 16 + lg * 4 + r;
        __builtin_nontemporal_store(
            p, &attn_out[((size_t)sh * Bd + row) * Bd + ct * 64 + c2 * 16 + lr]);
        Pb[w][(lg * 4 + r) * 72 + c2 * 16 + lr] = f2bf(p);
      }
    }
#pragma unroll
    for (int ks2 = 0; ks2 < 2; ++ks2) {
      bf16x8 pa = *(const bf16x8*)&Pb[w][lr * 72 + ks2 * 32 + lg * 8];
#pragma unroll
      for (int dt = 0; dt < 4; ++dt) {
        bf16x8 bv = *(const bf16x8*)&Vs[(dt * 16 + lr) * 72 + ks2 * 32 + lg * 8];
        cacc[dt] = __builtin_amdgcn_mfma_f32_16x16x32_bf16(pa, bv, cacc[dt], 0, 0, 0);
      }
    }
  }

#pragma unroll
  for (int dt = 0; dt < 4; ++dt) {
#pragma unroll
    for (int r = 0; r < 4; ++r) {
      int row = row0 + w * 16 + lg * 4 + r;
      size_t i = (size_t)s * Bd + row;
      int j = h * 64 + dt * 16 + lr;
      ctx_out[i * Ed + j] = f2bf(cacc[dt][r]);
    }
  }
}

// ---------------------------------------------------------------------------
// Output projection, 128x128 tile: x[i,j] = sum_k ctx[i,k]*Wo[j,k]+bo[j]+Q[i,j]
// ctx bf16 (8192,768), Wo f32. grid (64, 6), block 256.
// ---------------------------------------------------------------------------
__global__ __launch_bounds__(256, 2) void proj_kernel(
    const unsigned short* __restrict__ ctx, const float* __restrict__ Wo,
    const float* __restrict__ bo, const float* __restrict__ Qin,
    float* __restrict__ xout) {
  __shared__ unsigned short As[128 * 72];
  __shared__ unsigned short Bs[128 * 72];
  const int i0 = blockIdx.x * 128;
  const int j0 = blockIdx.y * 128;
  const int t = threadIdx.x;
  const int w = t >> 6, l = t & 63, lr = l & 15, lg = l >> 4;
  const int wr = w >> 1, wc = w & 1;

  f32x4 acc[4][4] = {};

  for (int k0 = 0; k0 < Ed; k0 += 64) {
    u16x8 pa[4];
    uint2 pb[8];
#pragma unroll
    for (int q = 0; q < 4; ++q) {
      int flat = t + 256 * q;
      int row = flat >> 3;
      int c8 = (flat & 7) * 8;
      pa[q] = *(const u16x8*)(ctx + (size_t)(i0 + row) * Ed + k0 + c8);
    }
#pragma unroll
    for (int q = 0; q < 8; ++q) {
      int flat = t + 256 * q;
      int row = flat >> 4;
      int c4 = (flat & 15) * 4;
      float4 vb = *(const float4*)(Wo + (size_t)(j0 + row) * Ed + k0 + c4);
      pb[q] = make_uint2(pk2(vb.x, vb.y), pk2(vb.z, vb.w));
    }
    __syncthreads();
#pragma unroll
    for (int q = 0; q < 4; ++q) {
      int flat = t + 256 * q;
      int row = flat >> 3;
      int c8 = (flat & 7) * 8;
      *(u16x8*)&As[row * 72 + c8] = pa[q];
    }
#pragma unroll
    for (int q = 0; q < 8; ++q) {
      int flat = t + 256 * q;
      int row = flat >> 4;
      int c4 = (flat & 15) * 4;
      *(uint2*)&Bs[row * 72 + c4] = pb[q];
    }
    __syncthreads();
#pragma unroll
    for (int ks = 0; ks < 2; ++ks) {
      bf16x8 af[4], bf[4];
#pragma unroll
      for (int fr = 0; fr < 4; ++fr)
        af[fr] = *(const bf16x8*)&As[(wr * 64 + fr * 16 + lr) * 72 + ks * 32 + lg * 8];
#pragma unroll
      for (int fc = 0; fc < 4; ++fc)
        bf[fc] = *(const bf16x8*)&Bs[(wc * 64 + fc * 16 + lr) * 72 + ks * 32 + lg * 8];
#pragma unroll
      for (int fr = 0; fr < 4; ++fr)
#pragma unroll
        for (int fc = 0; fc < 4; ++fc)
          acc[fr][fc] = __builtin_amdgcn_mfma_f32_16x16x32_bf16(af[fr], bf[fc], acc[fr][fc], 0, 0, 0);
    }
  }

#pragma unroll
  for (int fr = 0; fr < 4; ++fr) {
#pragma unroll
    for (int fc = 0; fc < 4; ++fc) {
      int j = j0 + wc * 64 + fc * 16 + lr;
      float bv_ = bo[j];
#pragma unroll
      for (int r = 0; r < 4; ++r) {
        int i = i0 + wr * 64 + fr * 16 + lg * 4 + r;
        float v = acc[fr][fc][r] + bv_ + Qin[(size_t)i * Ed + j];
        xout[(size_t)i * Ed + j] = v;
      }
    }
  }
}

// ---------------------------------------------------------------------------
// Row LayerNorm over E=768.  grid (8192), block 256.
// ---------------------------------------------------------------------------
__global__ __launch_bounds__(256) void ln_kernel(
    const float* __restrict__ x, const float* __restrict__ g,
    const float* __restrict__ bb, float* __restrict__ out) {
  const int i = blockIdx.x;
  const int t = threadIdx.x;
  const float* xr = x + (size_t)i * Ed;
  float v0 = xr[t], v1 = xr[t + 256], v2 = xr[t + 512];
  float s1 = v0 + v1 + v2;
  float s2 = v0 * v0 + v1 * v1 + v2 * v2;
#pragma unroll
  for (int mk = 1; mk < 64; mk <<= 1) {
    s1 += __shfl_xor(s1, mk, 64);
    s2 += __shfl_xor(s2, mk, 64);
  }
  __shared__ float red[8];
  const int w = t >> 6, l = t & 63;
  if (l == 0) { red[w] = s1; red[w + 4] = s2; }
  __syncthreads();
  s1 = red[0] + red[1] + red[2] + red[3];
  s2 = red[4] + red[5] + red[6] + red[7];
  float mu = s1 * (1.0f / 768.0f);
  float var = s2 * (1.0f / 768.0f) - mu * mu;
  float rs = rsqrtf(var + 1e-5f);
  float* orow = out + (size_t)i * Ed;
  orow[t] = (v0 - mu) * rs * g[t] + bb[t];
  orow[t + 256] = (v1 - mu) * rs * g[t + 256] + bb[t + 256];
  orow[t + 512] = (v2 - mu) * rs * g[t + 512] + bb[t + 512];
}

extern "C" void kernel_launch(void* const* d_in, const int* in_sizes, int n_in,
                              void* d_out, int out_size, void* d_ws, size_t ws_size,
                              hipStream_t stream) {
  (void)in_sizes; (void)n_in; (void)out_size; (void)ws_size;
  const float* Qin = (const float*)d_in[0];
  const float* Kin = (const float*)d_in[1];
  const float* Vin = (const float*)d_in[2];
  const float* Wq = (const float*)d_in[3];
  const float* bq = (const float*)d_in[4];
  const float* Wk = (const float*)d_in[5];
  const float* bk = (const float*)d_in[6];
  const float* Wv = (const float*)d_in[7];
  const float* bv = (const float*)d_in[8];
  const float* Wo = (const float*)d_in[9];
  const float* bo = (const float*)d_in[10];
  const float* ln_g = (const float*)d_in[11];
  const float* ln_b = (const float*)d_in[12];

  float* outp = (float*)d_out;
  float* normed = outp;
  float* attn_out = outp + (size_t)SBd * Ed;

  char* ws = (char*)d_ws;
  unsigned short* qws = (unsigned short*)ws;
  unsigned short* kws = qws + 6291456;
  unsigned short* vws = kws + 6291456;   // [sh][d][b] transposed
  unsigned short* ctxws = vws + 6291456;
  float* xws = (float*)(ws + (size_t)4 * 12582912);

  hipLaunchKernelGGL(qkv_kernel, dim3(64, 6, 3), dim3(256), 0, stream,
                     Qin, Kin, Vin, Wq, bq, Wk, bk, Wv, bv, qws, kws, vws);
  hipLaunchKernelGGL(attn_kernel, dim3(8, 96), dim3(512), 0, stream,
                     qws, kws, vws, attn_out, ctxws);
  hipLaunchKernelGGL(proj_kernel, dim3(64, 6), dim3(256), 0, stream,
                     ctxws, Wo, bo, Qin, xws);
  hipLaunchKernelGGL(ln_kernel, dim3(8192), dim3(256), 0, stream,
                     xws, ln_g, ln_b, normed);
}

// Round 8
// 261.206 us; speedup vs baseline: 1.3302x; 1.0033x over previous
//
#include <hip/hip_runtime.h>
#include <hip/hip_bf16.h>
#include <math.h>

#define Sd 8
#define Bd 1024
#define Ed 768
#define Hd 12
#define Dd 64
#define SBd 8192

typedef short bf16x8 __attribute__((ext_vector_type(8)));
typedef unsigned short u16x8 __attribute__((ext_vector_type(8)));
typedef float f32x4 __attribute__((ext_vector_type(4)));

// log2(e)/8 : folded into q so attention scores are exp2-ready
#define QSC 0.18033688011112043f

// lgkmcnt-only barrier: does NOT drain vmcnt -> in-flight global stores/loads
// keep streaming across tiles (T4: never drain vmcnt in the main loop).
#define BARRIER()                                        \
  do {                                                   \
    asm volatile("s_waitcnt lgkmcnt(0)" ::: "memory");   \
    __builtin_amdgcn_s_barrier();                        \
    asm volatile("" ::: "memory");                       \
  } while (0)

// Native f32->bf16 (v_cvt_pk_bf16_f32 on gfx950), RNE. memcpy avoids the
// non-trivially-copyable bit_cast issue (round-4 lesson).
static __device__ __forceinline__ unsigned short f2bf(float f) {
  __hip_bfloat16 h = __float2bfloat16(f);
  unsigned short u;
  __builtin_memcpy(&u, &h, 2);
  return u;
}

static __device__ __forceinline__ unsigned int pk2(float lo, float hi) {
  __hip_bfloat162 h = __float22bfloat162_rn(make_float2(lo, hi));
  unsigned int u;
  __builtin_memcpy(&u, &h, 4);
  return u;
}

// ---------------------------------------------------------------------------
// QKV projection, 128x128 tile. X:(8192,768) f32, W:(768,768) f32.
// z=0: q -> [s][h][b][d] bf16 scaled by QSC; z=1: k -> [s][h][b][d];
// z=2: v -> [s][h][d][b] bf16 (transposed scatter epilogue).
// grid (64, 6, 3), block 256 (4 waves; wave = 64x64 output, 4x4 frags).
// ---------------------------------------------------------------------------
__global__ __launch_bounds__(256, 2) void qkv_kernel(
    const float* __restrict__ Qin, const float* __restrict__ Kin,
    const float* __restrict__ Vin,
    const float* __restrict__ Wq, const float* __restrict__ bq,
    const float* __restrict__ Wk, const float* __restrict__ bk,
    const float* __restrict__ Wv, const float* __restrict__ bv,
    unsigned short* __restrict__ qo, unsigned short* __restrict__ ko,
    unsigned short* __restrict__ vo) {
  __shared__ unsigned short As[128 * 72];
  __shared__ unsigned short Bs[128 * 72];
  const float* X;
  const float* W;
  const float* bias;
  switch (blockIdx.z) {
    case 0: X = Qin; W = Wq; bias = bq; break;
    case 1: X = Kin; W = Wk; bias = bk; break;
    default: X = Vin; W = Wv; bias = bv; break;
  }
  const int i0 = blockIdx.x * 128;
  const int j0 = blockIdx.y * 128;
  const int t = threadIdx.x;
  const int w = t >> 6, l = t & 63, lr = l & 15, lg = l >> 4;
  const int wr = w >> 1, wc = w & 1;

  f32x4 acc[4][4] = {};

  for (int k0 = 0; k0 < Ed; k0 += 64) {
    uint2 pa[8], pb[8];
#pragma unroll
    for (int q = 0; q < 8; ++q) {
      int flat = t + 256 * q;           // float4 units
      int row = flat >> 4;              // 0..127
      int c4 = (flat & 15) * 4;         // float col 0..60
      float4 va = *(const float4*)(X + (size_t)(i0 + row) * Ed + k0 + c4);
      float4 vb = *(const float4*)(W + (size_t)(j0 + row) * Ed + k0 + c4);
      pa[q] = make_uint2(pk2(va.x, va.y), pk2(va.z, va.w));
      pb[q] = make_uint2(pk2(vb.x, vb.y), pk2(vb.z, vb.w));
    }
    __syncthreads();
#pragma unroll
    for (int q = 0; q < 8; ++q) {
      int flat = t + 256 * q;
      int row = flat >> 4;
      int c4 = (flat & 15) * 4;
      *(uint2*)&As[row * 72 + c4] = pa[q];
      *(uint2*)&Bs[row * 72 + c4] = pb[q];
    }
    __syncthreads();
#pragma unroll
    for (int ks = 0; ks < 2; ++ks) {
      bf16x8 af[4], bf[4];
#pragma unroll
      for (int fr = 0; fr < 4; ++fr)
        af[fr] = *(const bf16x8*)&As[(wr * 64 + fr * 16 + lr) * 72 + ks * 32 + lg * 8];
#pragma unroll
      for (int fc = 0; fc < 4; ++fc)
        bf[fc] = *(const bf16x8*)&Bs[(wc * 64 + fc * 16 + lr) * 72 + ks * 32 + lg * 8];
#pragma unroll
      for (int fr = 0; fr < 4; ++fr)
#pragma unroll
        for (int fc = 0; fc < 4; ++fc)
          acc[fr][fc] = __builtin_amdgcn_mfma_f32_16x16x32_bf16(af[fr], bf[fc], acc[fr][fc], 0, 0, 0);
    }
  }

  const int z = blockIdx.z;
  if (z < 2) {
    unsigned short* out = (z == 0) ? qo : ko;
    const float sc = (z == 0) ? QSC : 1.0f;
#pragma unroll
    for (int fr = 0; fr < 4; ++fr) {
#pragma unroll
      for (int fc = 0; fc < 4; ++fc) {
        int colg = j0 + wc * 64 + fc * 16 + lr;
        int h = colg >> 6, d = colg & 63;
        float bv_ = bias[colg];
#pragma unroll
        for (int r = 0; r < 4; ++r) {
          int i = i0 + wr * 64 + fr * 16 + lg * 4 + r;
          int s = i >> 10, b = i & 1023;
          float v = (acc[fr][fc][r] + bv_) * sc;
          out[((((size_t)s * Hd + h) * Bd + b) << 6) + d] = f2bf(v);
        }
      }
    }
  } else {
#pragma unroll
    for (int fr = 0; fr < 4; ++fr) {
#pragma unroll
      for (int fc = 0; fc < 4; ++fc) {
        int colg = j0 + wc * 64 + fc * 16 + lr;
        int h = colg >> 6, d = colg & 63;
        float bv_ = bias[colg];
#pragma unroll
        for (int r = 0; r < 4; ++r) {
          int i = i0 + wr * 64 + fr * 16 + lg * 4 + r;
          int s = i >> 10, b = i & 1023;
          float v = acc[fr][fc][r] + bv_;
          vo[(((size_t)s * Hd + h) * 64 + d) * Bd + b] = f2bf(v);
        }
      }
    }
  }
}

// ---------------------------------------------------------------------------
// Attention per (s,h). Two-pass (recompute QK^T), scores pre-scaled for exp2,
// no max tracking. QBLK=128: 8 waves x 16 q-rows; K/V staged once per 128
// rows. lgkmcnt-only barriers; reg prefetch; nontemporal attn stores.
// grid (96, 8): sh on x so all 8 q-blocks of one (s,h) land on XCD sh%8
// (96 % 8 == 0) -> K/V stay in that XCD's L2 (12 sh x 256KB = 3MB < 4MB).
// block 512.
// ---------------------------------------------------------------------------
__global__ __launch_bounds__(512) void attn_kernel(
    const unsigned short* __restrict__ qb, const unsigned short* __restrict__ kb,
    const unsigned short* __restrict__ vt, float* __restrict__ attn_out,
    unsigned short* __restrict__ ctx_out) {
  __shared__ unsigned short Ks[64 * 72];
  __shared__ unsigned short Vs[64 * 72];
  __shared__ unsigned short Pb[8][16 * 72];
  const int sh = blockIdx.x;
  const int s = sh / Hd, h = sh % Hd;
  const int row0 = blockIdx.y * 128;
  const size_t base = (size_t)sh * Bd * 64;
  const int t = threadIdx.x;
  const int w = t >> 6, l = t & 63, lr = l & 15, lg = l >> 4;
  const int srow = t >> 3, skg = (t & 7) * 8;   // 512 thr x 16B = one 8KB tile

  const int qrow = row0 + w * 16 + lr;
  const bf16x8 aq0 = *(const bf16x8*)(qb + base + (size_t)qrow * 64 + lg * 8);
  const bf16x8 aq1 = *(const bf16x8*)(qb + base + (size_t)qrow * 64 + 32 + lg * 8);

  float lsum[4] = {0.f, 0.f, 0.f, 0.f};

  // ---- pass 1: denominators ----
  {
    const unsigned short* kp = kb + base + (size_t)srow * 64 + skg;
    u16x8 k0 = *(const u16x8*)kp;
    for (int ct = 0; ct < 16; ++ct) {
      BARRIER();
      *(u16x8*)&Ks[srow * 72 + skg] = k0;
      BARRIER();
      if (ct < 15) {
        const unsigned short* kn = kb + base + (size_t)((ct + 1) * 64 + srow) * 64 + skg;
        k0 = *(const u16x8*)kn;
      }
      f32x4 scv[4] = {};
#pragma unroll
      for (int ks = 0; ks < 2; ++ks) {
        bf16x8 a = ks ? aq1 : aq0;
#pragma unroll
        for (int c2 = 0; c2 < 4; ++c2) {
          bf16x8 bb = *(const bf16x8*)&Ks[(c2 * 16 + lr) * 72 + ks * 32 + lg * 8];
          scv[c2] = __builtin_amdgcn_mfma_f32_16x16x32_bf16(a, bb, scv[c2], 0, 0, 0);
        }
      }
#pragma unroll
      for (int c2 = 0; c2 < 4; ++c2)
#pragma unroll
        for (int r = 0; r < 4; ++r)
          lsum[r] += __builtin_amdgcn_exp2f(scv[c2][r]);
    }
  }
#pragma unroll
  for (int r = 0; r < 4; ++r) {
    float s1 = lsum[r];
    s1 += __shfl_xor(s1, 1, 16);
    s1 += __shfl_xor(s1, 2, 16);
    s1 += __shfl_xor(s1, 4, 16);
    s1 += __shfl_xor(s1, 8, 16);
    lsum[r] = 1.0f / s1;  // inverse denom for row lg*4+r (uniform across lr)
  }

  // ---- pass 2: recompute, write attn (nontemporal), PV ----
  f32x4 cacc[4] = {};
  const unsigned short* vbase = vt + (size_t)sh * 64 * Bd;
  u16x8 k0, v0;
  {
    const unsigned short* kp = kb + base + (size_t)srow * 64 + skg;
    k0 = *(const u16x8*)kp;
    const unsigned short* vp = vbase + (size_t)srow * Bd + skg;  // V^T row d
    v0 = *(const u16x8*)vp;
  }
  for (int ct = 0; ct < 16; ++ct) {
    BARRIER();
    *(u16x8*)&Ks[srow * 72 + skg] = k0;
    *(u16x8*)&Vs[srow * 72 + skg] = v0;
    BARRIER();
    if (ct < 15) {
      const unsigned short* kn = kb + base + (size_t)((ct + 1) * 64 + srow) * 64 + skg;
      k0 = *(const u16x8*)kn;
      const unsigned short* vn = vbase + (size_t)srow * Bd + (ct + 1) * 64 + skg;
      v0 = *(const u16x8*)vn;
    }
    f32x4 scv[4] = {};
#pragma unroll
    for (int ks = 0; ks < 2; ++ks) {
      bf16x8 a = ks ? aq1 : aq0;
#pragma unroll
      for (int c2 = 0; c2 < 4; ++c2) {
        bf16x8 bb = *(const bf16x8*)&Ks[(c2 * 16 + lr) * 72 + ks * 32 + lg * 8];
        scv[c2] = __builtin_amdgcn_mfma_f32_16x16x32_bf16(a, bb, scv[c2], 0, 0, 0);
      }
    }
#pragma unroll
    for (int c2 = 0; c2 < 4; ++c2) {
#pragma unroll
      for (int r = 0; r < 4; ++r) {
        float p = __builtin_amdgcn_exp2f(scv[c2][r]) * lsum[r];
        int row = row0 + w * 16 + lg * 4 + r;
        __builtin_nontemporal_store(
            p, &attn_out[((size_t)sh * Bd + row) * Bd + ct * 64 + c2 * 16 + lr]);
        Pb[w][(lg * 4 + r) * 72 + c2 * 16 + lr] = f2bf(p);
      }
    }
#pragma unroll
    for (int ks2 = 0; ks2 < 2; ++ks2) {
      bf16x8 pa = *(const bf16x8*)&Pb[w][lr * 72 + ks2 * 32 + lg * 8];
#pragma unroll
      for (int dt = 0; dt < 4; ++dt) {
        bf16x8 bv = *(const bf16x8*)&Vs[(dt * 16 + lr) * 72 + ks2 * 32 + lg * 8];
        cacc[dt] = __builtin_amdgcn_mfma_f32_16x16x32_bf16(pa, bv, cacc[dt], 0, 0, 0);
      }
    }
  }

#pragma unroll
  for (int dt = 0; dt < 4; ++dt) {
#pragma unroll
    for (int r = 0; r < 4; ++r) {
      int row = row0 + w * 16 + lg * 4 + r;
      size_t i = (size_t)s * Bd + row;
      int j = h * 64 + dt * 16 + lr;
      ctx_out[i * Ed + j] = f2bf(cacc[dt][r]);
    }
  }
}

// ---------------------------------------------------------------------------
// Output projection, 128x128 tile: x[i,j] = sum_k ctx[i,k]*Wo[j,k]+bo[j]+Q[i,j]
// ctx bf16 (8192,768), Wo f32. grid (64, 6), block 256.
// ---------------------------------------------------------------------------
__global__ __launch_bounds__(256, 2) void proj_kernel(
    const unsigned short* __restrict__ ctx, const float* __restrict__ Wo,
    const float* __restrict__ bo, const float* __restrict__ Qin,
    float* __restrict__ xout) {
  __shared__ unsigned short As[128 * 72];
  __shared__ unsigned short Bs[128 * 72];
  const int i0 = blockIdx.x * 128;
  const int j0 = blockIdx.y * 128;
  const int t = threadIdx.x;
  const int w = t >> 6, l = t & 63, lr = l & 15, lg = l >> 4;
  const int wr = w >> 1, wc = w & 1;

  f32x4 acc[4][4] = {};

  for (int k0 = 0; k0 < Ed; k0 += 64) {
    u16x8 pa[4];
    uint2 pb[8];
#pragma unroll
    for (int q = 0; q < 4; ++q) {
      int flat = t + 256 * q;
      int row = flat >> 3;
      int c8 = (flat & 7) * 8;
      pa[q] = *(const u16x8*)(ctx + (size_t)(i0 + row) * Ed + k0 + c8);
    }
#pragma unroll
    for (int q = 0; q < 8; ++q) {
      int flat = t + 256 * q;
      int row = flat >> 4;
      int c4 = (flat & 15) * 4;
      float4 vb = *(const float4*)(Wo + (size_t)(j0 + row) * Ed + k0 + c4);
      pb[q] = make_uint2(pk2(vb.x, vb.y), pk2(vb.z, vb.w));
    }
    __syncthreads();
#pragma unroll
    for (int q = 0; q < 4; ++q) {
      int flat = t + 256 * q;
      int row = flat >> 3;
      int c8 = (flat & 7) * 8;
      *(u16x8*)&As[row * 72 + c8] = pa[q];
    }
#pragma unroll
    for (int q = 0; q < 8; ++q) {
      int flat = t + 256 * q;
      int row = flat >> 4;
      int c4 = (flat & 15) * 4;
      *(uint2*)&Bs[row * 72 + c4] = pb[q];
    }
    __syncthreads();
#pragma unroll
    for (int ks = 0; ks < 2; ++ks) {
      bf16x8 af[4], bf[4];
#pragma unroll
      for (int fr = 0; fr < 4; ++fr)
        af[fr] = *(const bf16x8*)&As[(wr * 64 + fr * 16 + lr) * 72 + ks * 32 + lg * 8];
#pragma unroll
      for (int fc = 0; fc < 4; ++fc)
        bf[fc] = *(const bf16x8*)&Bs[(wc * 64 + fc * 16 + lr) * 72 + ks * 32 + lg * 8];
#pragma unroll
      for (int fr = 0; fr < 4; ++fr)
#pragma unroll
        for (int fc = 0; fc < 4; ++fc)
          acc[fr][fc] = __builtin_amdgcn_mfma_f32_16x16x32_bf16(af[fr], bf[fc], acc[fr][fc], 0, 0, 0);
    }
  }

#pragma unroll
  for (int fr = 0; fr < 4; ++fr) {
#pragma unroll
    for (int fc = 0; fc < 4; ++fc) {
      int j = j0 + wc * 64 + fc * 16 + lr;
      float bv_ = bo[j];
#pragma unroll
      for (int r = 0; r < 4; ++r) {
        int i = i0 + wr * 64 + fr * 16 + lg * 4 + r;
        float v = acc[fr][fc][r] + bv_ + Qin[(size_t)i * Ed + j];
        xout[(size_t)i * Ed + j] = v;
      }
    }
  }
}

// ---------------------------------------------------------------------------
// Row LayerNorm over E=768.  grid (8192), block 256.
// ---------------------------------------------------------------------------
__global__ __launch_bounds__(256) void ln_kernel(
    const float* __restrict__ x, const float* __restrict__ g,
    const float* __restrict__ bb, float* __restrict__ out) {
  const int i = blockIdx.x;
  const int t = threadIdx.x;
  const float* xr = x + (size_t)i * Ed;
  float v0 = xr[t], v1 = xr[t + 256], v2 = xr[t + 512];
  float s1 = v0 + v1 + v2;
  float s2 = v0 * v0 + v1 * v1 + v2 * v2;
#pragma unroll
  for (int mk = 1; mk < 64; mk <<= 1) {
    s1 += __shfl_xor(s1, mk, 64);
    s2 += __shfl_xor(s2, mk, 64);
  }
  __shared__ float red[8];
  const int w = t >> 6, l = t & 63;
  if (l == 0) { red[w] = s1; red[w + 4] = s2; }
  __syncthreads();
  s1 = red[0] + red[1] + red[2] + red[3];
  s2 = red[4] + red[5] + red[6] + red[7];
  float mu = s1 * (1.0f / 768.0f);
  float var = s2 * (1.0f / 768.0f) - mu * mu;
  float rs = rsqrtf(var + 1e-5f);
  float* orow = out + (size_t)i * Ed;
  orow[t] = (v0 - mu) * rs * g[t] + bb[t];
  orow[t + 256] = (v1 - mu) * rs * g[t + 256] + bb[t + 256];
  orow[t + 512] = (v2 - mu) * rs * g[t + 512] + bb[t + 512];
}

extern "C" void kernel_launch(void* const* d_in, const int* in_sizes, int n_in,
                              void* d_out, int out_size, void* d_ws, size_t ws_size,
                              hipStream_t stream) {
  (void)in_sizes; (void)n_in; (void)out_size; (void)ws_size;
  const float* Qin = (const float*)d_in[0];
  const float* Kin = (const float*)d_in[1];
  const float* Vin = (const float*)d_in[2];
  const float* Wq = (const float*)d_in[3];
  const float* bq = (const float*)d_in[4];
  const float* Wk = (const float*)d_in[5];
  const float* bk = (const float*)d_in[6];
  const float* Wv = (const float*)d_in[7];
  const float* bv = (const float*)d_in[8];
  const float* Wo = (const float*)d_in[9];
  const float* bo = (const float*)d_in[10];
  const float* ln_g = (const float*)d_in[11];
  const float* ln_b = (const float*)d_in[12];

  float* outp = (float*)d_out;
  float* normed = outp;
  float* attn_out = outp + (size_t)SBd * Ed;

  char* ws = (char*)d_ws;
  unsigned short* qws = (unsigned short*)ws;
  unsigned short* kws = qws + 6291456;
  unsigned short* vws = kws + 6291456;   // [sh][d][b] transposed
  unsigned short* ctxws = vws + 6291456;
  float* xws = (float*)(ws + (size_t)4 * 12582912);

  hipLaunchKernelGGL(qkv_kernel, dim3(64, 6, 3), dim3(256), 0, stream,
                     Qin, Kin, Vin, Wq, bq, Wk, bk, Wv, bv, qws, kws, vws);
  hipLaunchKernelGGL(attn_kernel, dim3(96, 8), dim3(512), 0, stream,
                     qws, kws, vws, attn_out, ctxws);
  hipLaunchKernelGGL(proj_kernel, dim3(64, 6), dim3(256), 0, stream,
                     ctxws, Wo, bo, Qin, xws);
  hipLaunchKernelGGL(ln_kernel, dim3(8192), dim3(256), 0, stream,
                     xws, ln_g, ln_b, normed);
}